// Round 1
// baseline (142.990 us; speedup 1.0000x reference)
//
#include <hip/hip_runtime.h>

#define FDIM 256
#define HALF 128
#define NSAMP 10
#define NEGF -9.0e15f

// Evidence-pinned dtypes (rounds 0-3 of prior session):
//  - features: fp32, output: fp32, indices width auto-detected per-wave via odd-word ballot.
//
// V2 structure (this round): 2 waves per node, each owning 128 of the 256 features.
//  - 8192 waves -> 8 blocks/CU -> 32 waves/CU (vs 16 before): attacks the
//    latency-bound 3-round index chain (nidx -> uid -> embed row).
//  - lane-owns-score register layout (score s lives in lane s) to fit <=64 VGPR
//    so __launch_bounds__(256,8) actually yields 8 waves/EU.
//  - cross-wave dot combine via 256B LDS + one __syncthreads.

__global__ __launch_bounds__(256, 8) void AttentionAggregator_42477226557515_kernel(
    const float* __restrict__ features,   // [VOCAB, FDIM] fp32
    const int* __restrict__ nodes_w,      // [N] int32/int64 word view
    const int* __restrict__ uids_w,       // [M]
    const int* __restrict__ nidx_w,       // [N, NSAMP]
    float* __restrict__ out,              // [N, FDIM] fp32
    int n_nodes)
{
    __shared__ float part[4][16];         // [wave][score] partial dots, padded

    const int lane = threadIdx.x & 63;
    const int wid  = threadIdx.x >> 6;    // 0..3: waves 0,1 = node A halves; 2,3 = node B
    const int half = wid & 1;
    int n = (blockIdx.x << 1) + (wid >> 1);
    const bool live = (n < n_nodes);
    if (!live) n = 0;                     // clamp: keep wave in the barrier, skip store

    // index-width detection: int64 positive ids -> all odd words zero
    const unsigned long long oddnz = __ballot(nodes_w[2 * lane + 1] != 0);
    const bool i64 = (oddnz == 0ULL);

    const int off = half * HALF + (lane << 1);   // 2 fp32 per lane = 8B vector

    // self feature half-row (issued first, independent of the index chain)
    const int node_id = i64 ? nodes_w[2 * n] : nodes_w[n];
    const float2 sr = *(const float2*)(features + (size_t)node_id * FDIM + off);

    // ---- lane-parallel index fetch: lanes 0..9 own one neighbor column ----
    int c_own = 0;
    if (lane < NSAMP) {
        const int j = n * NSAMP + lane;
        c_own = i64 ? nidx_w[2 * j] : nidx_w[j];
    }
    int u_own = 0;
    if (lane < NSAMP)
        u_own = i64 ? uids_w[2 * c_own] : uids_w[c_own];

    // lane-parallel dedupe: lane s is invalid if some t<s has the same column
    // (mask .set(1.0) is idempotent per column)
    bool vown = true;
#pragma unroll
    for (int t = 0; t < NSAMP; ++t) {
        const int ct = __shfl(c_own, t, 64);
        if (t < lane && ct == c_own) vown = false;
    }

    // issue all 10 embed half-row loads (independent, all in flight)
    float2 e[NSAMP];
#pragma unroll
    for (int s = 0; s < NSAMP; ++s) {
        const int u = __shfl(u_own, s, 64);
        e[s] = *(const float2*)(features + (size_t)u * FDIM + off);
    }

    // partial dots over this wave's 128 features; butterfly-reduce, deposit in lane s
    float part_own = 0.0f;
#pragma unroll
    for (int s = 0; s < NSAMP; ++s) {
        float p = sr.x * e[s].x + sr.y * e[s].y;
#pragma unroll
        for (int d = 32; d > 0; d >>= 1) p += __shfl_xor(p, d, 64);
        if (lane == s) part_own = p;
    }

    // cross-wave combine: each node's two halves sum their partial dots
    if (lane < NSAMP) part[wid][lane] = part_own;
    __syncthreads();
    const int partner = wid ^ 1;
    float sc_own = NEGF;
    if (lane < NSAMP && vown)
        sc_own = part[wid][lane] + part[partner][lane];

    // lane-parallel softmax over lanes 0..9 (full-wave butterflies so every
    // lane ends with the correct m, l for its output store)
    float m = sc_own;
#pragma unroll
    for (int d = 32; d > 0; d >>= 1) m = fmaxf(m, __shfl_xor(m, d, 64));
    float w_own = (lane < NSAMP && vown) ? __expf(sc_own - m) : 0.0f;
    float l = w_own;
#pragma unroll
    for (int d = 32; d > 0; d >>= 1) l += __shfl_xor(l, d, 64);
    const float inv = 1.0f / l;

    // weighted sum over this wave's half of the embed rows (still in registers)
    float a0 = 0.0f, a1 = 0.0f;
#pragma unroll
    for (int s = 0; s < NSAMP; ++s) {
        const float ws = __shfl(w_own, s, 64);
        a0 += ws * e[s].x;
        a1 += ws * e[s].y;
    }

    if (live) {
        float2 o;
        o.x = a0 * inv;
        o.y = a1 * inv;
        *(float2*)(out + (size_t)n * FDIM + off) = o;
    }
}

extern "C" void kernel_launch(void* const* d_in, const int* in_sizes, int n_in,
                              void* d_out, int out_size, void* d_ws, size_t ws_size,
                              hipStream_t stream) {
    const float* features = (const float*)d_in[0];
    const int* nodes      = (const int*)d_in[1];
    const int* uids       = (const int*)d_in[2];
    const int* nidx       = (const int*)d_in[3];
    float* out            = (float*)d_out;

    const int n_nodes = out_size / FDIM;            // 4096, dtype-proof
    const int blocks  = (n_nodes + 1) / 2;          // 2 nodes per 256-thread block

    hipLaunchKernelGGL(AttentionAggregator_42477226557515_kernel,
                       dim3(blocks), dim3(256), 0, stream,
                       features, nodes, uids, nidx, out, n_nodes);
}

// Round 2
// 137.520 us; speedup vs baseline: 1.0398x; 1.0398x over previous
//
#include <hip/hip_runtime.h>

#define FDIM 256
#define NSAMP 10
#define HALFS 5
#define NEGF -9.0e15f

// Evidence-pinned dtypes (prior session rounds 0-3):
//  - features: fp32, output: fp32, index width auto-detected per-wave via odd-word ballot.
//
// V3 structure: 2 waves per node, split by SAMPLES (not features).
//  - wave h of a node owns samples h*5..h*5+4, full 256-feature float4 lanes.
//  - 8192 waves -> 32 waves/CU (2x V1's 16) to hide the nidx->uid->embed chain,
//    WITHOUT halving load width or duplicating the butterfly work (V2's mistakes:
//    float2 gathers doubled VMEM instruction count; both half-waves re-did all work).
//  - cross-wave: 10-score exchange + partial-output combine via ~2.2KB LDS, 2 barriers.
//  - e[5] instead of e[10] keeps live set ~50 VGPR so __launch_bounds__(256,8) holds.

__global__ __launch_bounds__(256, 8) void AttentionAggregator_42477226557515_kernel(
    const float* __restrict__ features,   // [VOCAB, FDIM] fp32
    const int* __restrict__ nodes_w,      // [N] int32/int64 word view
    const int* __restrict__ uids_w,       // [M]
    const int* __restrict__ nidx_w,       // [N, NSAMP]
    float* __restrict__ out,              // [N, FDIM] fp32
    int n_nodes)
{
    __shared__ float  sc_sm[2][16];       // [node slot][sample] raw scores
    __shared__ float4 part[2][64];        // [node slot][lane] half-0 partial output

    const int lane = threadIdx.x & 63;
    const int wid  = threadIdx.x >> 6;    // 0..3
    const int nl   = wid >> 1;            // node slot within block (0,1)
    const int h    = wid & 1;             // sample-half (0: s=0..4, 1: s=5..9)
    int n = (blockIdx.x << 1) + nl;
    const bool live = (n < n_nodes);
    if (!live) n = 0;                     // clamp: stay in barriers, skip store

    // index-width detection: int64 positive ids -> all odd words zero
    const unsigned long long oddnz = __ballot(nodes_w[2 * lane + 1] != 0);
    const bool i64 = (oddnz == 0ULL);

    const int off = lane << 2;            // 4 fp32 per lane = 16B vector

    // self feature row (full 256 features; independent of the index chain)
    const int node_id = i64 ? nodes_w[2 * n] : nodes_w[n];
    const float4 srv = *(const float4*)(features + (size_t)node_id * FDIM + off);

    // lane-parallel index fetch: lanes 0..9 own one neighbor column.
    // Both half-waves load all 10 (dedupe needs every column; loads are tiny).
    int c_own = 0;
    if (lane < NSAMP) {
        const int j = n * NSAMP + lane;
        c_own = i64 ? nidx_w[2 * j] : nidx_w[j];
    }
    int u_own = 0;
    if (lane < NSAMP)
        u_own = i64 ? uids_w[2 * c_own] : uids_w[c_own];

    // lane-parallel dedupe: lane s invalid if some t<s has the same column
    // (mask .set(1.0) is idempotent per column)
    bool vown = true;
#pragma unroll
    for (int t = 0; t < NSAMP; ++t) {
        const int ct = __shfl(c_own, t, 64);
        if (t < lane && ct == c_own) vown = false;
    }

    // this wave's 5 embed rows, full-width float4 gathers, all in flight
    float4 e[HALFS];
#pragma unroll
    for (int s = 0; s < HALFS; ++s) {
        const int u = __shfl(u_own, h * HALFS + s, 64);
        e[s] = *(const float4*)(features + (size_t)u * FDIM + off);
    }

    // dots over all 256 features; butterfly-reduce; deposit score s in lane h*5+s
    float p_own = 0.0f;
#pragma unroll
    for (int s = 0; s < HALFS; ++s) {
        float p = srv.x * e[s].x + srv.y * e[s].y + srv.z * e[s].z + srv.w * e[s].w;
#pragma unroll
        for (int d = 32; d > 0; d >>= 1) p += __shfl_xor(p, d, 64);
        if (lane == h * HALFS + s) p_own = p;
    }
    if (lane >= h * HALFS && lane < (h + 1) * HALFS)
        sc_sm[nl][lane] = p_own;
    __syncthreads();

    // lane-parallel softmax over all 10 scores (each wave computes it in full;
    // lanes >=10 and invalid lanes carry NEG -> contribute nothing)
    float sc_own = NEGF;
    if (lane < NSAMP && vown) sc_own = sc_sm[nl][lane];
    float m = sc_own;
#pragma unroll
    for (int d = 32; d > 0; d >>= 1) m = fmaxf(m, __shfl_xor(m, d, 64));
    float w_own = (lane < NSAMP && vown) ? __expf(sc_own - m) : 0.0f;
    float l = w_own;
#pragma unroll
    for (int d = 32; d > 0; d >>= 1) l += __shfl_xor(l, d, 64);
    const float inv = 1.0f / l;

    // weighted sum over this wave's 5 embed rows (still in registers)
    float a0 = 0.f, a1 = 0.f, a2 = 0.f, a3 = 0.f;
#pragma unroll
    for (int s = 0; s < HALFS; ++s) {
        const float ws = __shfl(w_own, h * HALFS + s, 64);
        a0 += ws * e[s].x;
        a1 += ws * e[s].y;
        a2 += ws * e[s].z;
        a3 += ws * e[s].w;
    }

    // cross-wave output combine: half 0 deposits, half 1 adds + scales + stores
    if (h == 0) {
        float4 pv; pv.x = a0; pv.y = a1; pv.z = a2; pv.w = a3;
        part[nl][lane] = pv;
    }
    __syncthreads();
    if (h == 1 && live) {
        const float4 pv = part[nl][lane];
        float4 o;
        o.x = (a0 + pv.x) * inv;
        o.y = (a1 + pv.y) * inv;
        o.z = (a2 + pv.z) * inv;
        o.w = (a3 + pv.w) * inv;
        *(float4*)(out + (size_t)n * FDIM + off) = o;
    }
}

extern "C" void kernel_launch(void* const* d_in, const int* in_sizes, int n_in,
                              void* d_out, int out_size, void* d_ws, size_t ws_size,
                              hipStream_t stream) {
    const float* features = (const float*)d_in[0];
    const int* nodes      = (const int*)d_in[1];
    const int* uids       = (const int*)d_in[2];
    const int* nidx       = (const int*)d_in[3];
    float* out            = (float*)d_out;

    const int n_nodes = out_size / FDIM;            // 4096, dtype-proof
    const int blocks  = (n_nodes + 1) / 2;          // 2 nodes (4 waves) per block

    hipLaunchKernelGGL(AttentionAggregator_42477226557515_kernel,
                       dim3(blocks), dim3(256), 0, stream,
                       features, nodes, uids, nidx, out, n_nodes);
}